// Round 6
// baseline (950.006 us; speedup 1.0000x reference)
//
#include <hip/hip_runtime.h>

// Finger-mount frames (row-major 4x4), exact constants from the reference.
__constant__ float c_TFR[5][16] = {
    {0.429052f, -0.571046f, -0.699872f, 0.061f,
     0.187171f,  0.814201f, -0.549586f, 0.044f,
     0.883675f,  0.104806f,  0.456218f, 0.0885f,
     0.f, 0.f, 0.f, 1.f},
    {0.0f, -0.087156f, 0.996195f, -0.001429881f,
     0.0f, -0.996195f, -0.087156f, 0.036800135f,
     1.0f, 0.0f, 0.0f, 0.116743545f,
     0.f, 0.f, 0.f, 1.f},
    {0.0f, 0.0f, 1.0f, -0.0026f,
     0.0f, -1.0f, 0.0f, 0.01f,
     1.0f, 0.0f, 0.0f, 0.127043545f,
     0.f, 0.f, 0.f, 1.f},
    {0.0f, 0.087152f, 0.996195f, -0.001429881f,
     0.0f, -0.996195f, 0.087152f, -0.016800135f,
     1.0f, 0.0f, 0.0f, 0.122043545f,
     0.f, 0.f, 0.f, 1.f},
    {0.0f, 0.1736479f, 0.9848078f, 0.002071571f,
     0.0f, -0.9848078f, 0.1736479f, -0.043396306f,
     1.0f, 0.0f, 0.0f, 0.103043545f,
     0.f, 0.f, 0.f, 1.f},
};

__device__ __forceinline__ void mat4_mul(const float* __restrict__ A,
                                         const float* __restrict__ B,
                                         float* __restrict__ C) {
#pragma unroll
    for (int i = 0; i < 4; ++i) {
#pragma unroll
        for (int j = 0; j < 4; ++j) {
            C[i * 4 + j] = fmaf(A[i * 4 + 0], B[0 * 4 + j],
                           fmaf(A[i * 4 + 1], B[1 * 4 + j],
                           fmaf(A[i * 4 + 2], B[2 * 4 + j],
                                A[i * 4 + 3] * B[3 * 4 + j])));
        }
    }
}

// ---- rh output: out[b][n][0..2] = (pose[b] @ T) rows 0..2 . rh_v[n] ----
// grid: B * blocksPerB, block: 512. Each thread handles 4 vertices.
__global__ __launch_bounds__(512) void rh_kernel(
    const float* __restrict__ pose, const float* __restrict__ T,
    const float* __restrict__ rh_v, float* __restrict__ out,
    int blocksPerB, int slotsPerB /* = n_rh/4 */) {
    __shared__ float sM[12];
    int b = blockIdx.x / blocksPerB;
    int k = blockIdx.x - b * blocksPerB;
    if (threadIdx.x == 0) {
        float M[16];
        mat4_mul(pose + (long long)b * 16, T, M);
#pragma unroll
        for (int i = 0; i < 12; ++i) sM[i] = M[i];
    }
    __syncthreads();
    int slot = k * 512 + threadIdx.x;
    if (slot < slotsPerB) {
        float m[12];
#pragma unroll
        for (int i = 0; i < 12; ++i) m[i] = sM[i];
        const float4* v4 = reinterpret_cast<const float4*>(rh_v) + (long long)slot * 4;
        float res[12];
#pragma unroll
        for (int kk = 0; kk < 4; ++kk) {
            float4 v = v4[kk];
            res[kk * 3 + 0] = fmaf(m[0], v.x, fmaf(m[1], v.y, fmaf(m[2],  v.z, m[3]  * v.w)));
            res[kk * 3 + 1] = fmaf(m[4], v.x, fmaf(m[5], v.y, fmaf(m[6],  v.z, m[7]  * v.w)));
            res[kk * 3 + 2] = fmaf(m[8], v.x, fmaf(m[9], v.y, fmaf(m[10], v.z, m[11] * v.w)));
        }
        float4* op = reinterpret_cast<float4*>(out + (long long)b * (slotsPerB * 12LL) + (long long)slot * 12);
        op[0] = make_float4(res[0], res[1], res[2],  res[3]);
        op[1] = make_float4(res[4], res[5], res[6],  res[7]);
        op[2] = make_float4(res[8], res[9], res[10], res[11]);
    }
}

// ---- finger outputs: base/prox/med/dist. One block per (b, f, p). ----
// block: 384 threads; thread 0 builds the chain matrix, 375 threads do 4 verts each.
__global__ __launch_bounds__(384) void finger_kernel(
    const float* __restrict__ pose, const float* __restrict__ theta,
    const float* __restrict__ T, const float* __restrict__ base_v,
    const float* __restrict__ prox_v, const float* __restrict__ med_v,
    const float* __restrict__ dist_v, float* __restrict__ out /* start of base section */,
    long long partStride /* B*5*npart*3 */, int slots /* npart/4 */) {
    __shared__ float sP[12];
    int blk = blockIdx.x;
    int p  = blk & 3;
    int bf = blk >> 2;
    int f = bf % 5;
    int b = bf / 5;
    if (threadIdx.x == 0) {
        float M[16], W[16], P[16], Q[16];
        mat4_mul(pose + (long long)b * 16, T, M);
        mat4_mul(M, c_TFR[f], W);
        const float* th = theta + (long long)b * 20 + f * 4;
        // T01: dh(A=0, alpha=0, th=-th0) -> c=cos(th0), s=-sin(th0)
        {
            float c0 = cosf(th[0]);
            float s0 = -sinf(th[0]);
            float D[16] = {c0, -s0, 0.f, 0.f,
                           s0,  c0, 0.f, 0.f,
                           0.f, 0.f, 1.f, 0.f,
                           0.f, 0.f, 0.f, 1.f};
            mat4_mul(W, D, P);
        }
        if (p >= 1) {
            // T12: dh(0, pi/2, th1); ca = cos(float32(pi/2)), sa = 1.0f
            const float CA = -4.37113883e-08f;
            float c1 = cosf(th[1]), s1 = sinf(th[1]);
            float D[16] = {c1,      -s1,      0.f, 0.f,
                           s1 * CA,  c1 * CA, -1.f, 0.f,
                           s1,       c1,      CA,  0.f,
                           0.f,      0.f,     0.f, 1.f};
            mat4_mul(P, D, Q);
#pragma unroll
            for (int i = 0; i < 16; ++i) P[i] = Q[i];
        }
        if (p >= 2) {
            // T23: dh(A2=0.055, 0, th2)
            float c2 = cosf(th[2]), s2 = sinf(th[2]);
            float D[16] = {c2, -s2, 0.f, 0.055f,
                           s2,  c2, 0.f, 0.f,
                           0.f, 0.f, 1.f, 0.f,
                           0.f, 0.f, 0.f, 1.f};
            mat4_mul(P, D, Q);
#pragma unroll
            for (int i = 0; i < 16; ++i) P[i] = Q[i];
        }
        if (p >= 3) {
            // T34: dh(A3=0.025, 0, th3)
            float c3 = cosf(th[3]), s3 = sinf(th[3]);
            float D[16] = {c3, -s3, 0.f, 0.025f,
                           s3,  c3, 0.f, 0.f,
                           0.f, 0.f, 1.f, 0.f,
                           0.f, 0.f, 0.f, 1.f};
            mat4_mul(P, D, Q);
#pragma unroll
            for (int i = 0; i < 16; ++i) P[i] = Q[i];
        }
#pragma unroll
        for (int i = 0; i < 12; ++i) sP[i] = P[i];
    }
    __syncthreads();
    int t = threadIdx.x;
    if (t < slots) {
        const float* vsrc = (p == 0) ? base_v : (p == 1) ? prox_v : (p == 2) ? med_v : dist_v;
        float m[12];
#pragma unroll
        for (int i = 0; i < 12; ++i) m[i] = sP[i];
        const float4* v4 = reinterpret_cast<const float4*>(vsrc) + (long long)t * 4;
        float res[12];
#pragma unroll
        for (int kk = 0; kk < 4; ++kk) {
            float4 v = v4[kk];
            res[kk * 3 + 0] = fmaf(m[0], v.x, fmaf(m[1], v.y, fmaf(m[2],  v.z, m[3]  * v.w)));
            res[kk * 3 + 1] = fmaf(m[4], v.x, fmaf(m[5], v.y, fmaf(m[6],  v.z, m[7]  * v.w)));
            res[kk * 3 + 2] = fmaf(m[8], v.x, fmaf(m[9], v.y, fmaf(m[10], v.z, m[11] * v.w)));
        }
        long long off = (long long)p * partStride
                      + ((long long)(b * 5 + f)) * (slots * 12LL)
                      + (long long)t * 12;
        float4* op = reinterpret_cast<float4*>(out + off);
        op[0] = make_float4(res[0], res[1], res[2],  res[3]);
        op[1] = make_float4(res[4], res[5], res[6],  res[7]);
        op[2] = make_float4(res[8], res[9], res[10], res[11]);
    }
}

extern "C" void kernel_launch(void* const* d_in, const int* in_sizes, int n_in,
                              void* d_out, int out_size, void* d_ws, size_t ws_size,
                              hipStream_t stream) {
    const float* pose   = (const float*)d_in[0];
    const float* theta  = (const float*)d_in[1];
    const float* T      = (const float*)d_in[2];
    const float* rh_v   = (const float*)d_in[3];
    const float* base_v = (const float*)d_in[4];
    const float* prox_v = (const float*)d_in[5];
    const float* med_v  = (const float*)d_in[6];
    const float* dist_v = (const float*)d_in[7];
    float* out = (float*)d_out;

    int B      = in_sizes[0] / 16;   // 2048
    int n_rh   = in_sizes[3] / 4;    // 6000
    int n_part = in_sizes[4] / 4;    // 1500

    int rhSlots     = n_rh / 4;                  // 1500 (n_rh divisible by 4)
    int blocksPerB  = (rhSlots + 511) / 512;     // 3
    long long rhSize = (long long)B * n_rh * 3;  // 36,864,000 floats
    long long partStride = (long long)B * 5 * n_part * 3;  // 46,080,000 floats
    int fingerSlots = n_part / 4;                // 375

    rh_kernel<<<dim3(B * blocksPerB), dim3(512), 0, stream>>>(
        pose, T, rh_v, out, blocksPerB, rhSlots);

    finger_kernel<<<dim3(B * 5 * 4), dim3(384), 0, stream>>>(
        pose, theta, T, base_v, prox_v, med_v, dist_v,
        out + rhSize, partStride, fingerSlots);
}